// Round 20
// baseline (48.135 us; speedup 1.0000x reference)
//
#include <hip/hip_runtime.h>
#include <hip/hip_bf16.h>

#define B_ 32
#define L_ 512
#define H_ 1024
#define E_ 8
#define R_ 16

typedef float f32x4 __attribute__((ext_vector_type(4)));
typedef __bf16 bf16x8 __attribute__((ext_vector_type(8)));
typedef __bf16 bf16x4 __attribute__((ext_vector_type(4)));

static __device__ __forceinline__ __bf16 f2b(float f) { return (__bf16)f; }

static __device__ __forceinline__ f32x4 MFMA(bf16x8 a, bf16x8 b, f32x4 c) {
  return __builtin_amdgcn_mfma_f32_16x16x32_bf16(a, b, c, 0, 0, 0);
}

// ---------------- prep: f32 weights -> bf16 in ws; + gates -----------------
__global__ __launch_bounds__(256) void moe_prep_kernel(
    const float* __restrict__ x, const float* __restrict__ rw,
    const float* __restrict__ ldown, const float* __restrict__ lup,
    __bf16* __restrict__ ldb, __bf16* __restrict__ lub,
    float* __restrict__ gws)
{
  const int bid = blockIdx.x;
  if (bid < 256) {
    const int base = bid * 1024 + threadIdx.x * 4;
    const float* src; __bf16* dst; int off;
    if (base < 131072) { src = ldown; dst = ldb; off = base; }
    else               { src = lup;   dst = lub; off = base - 131072; }
    float4 v = *(const float4*)(src + off);
    bf16x4 bv = { f2b(v.x), f2b(v.y), f2b(v.z), f2b(v.w) };
    *(bf16x4*)(dst + off) = bv;
    return;
  }
  const int b = bid - 256;
  const int t = threadIdx.x;
  const int e = t >> 5, s = t & 31;
  const float* cls = x + (size_t)b * L_ * H_;
  const float* w   = rw + (size_t)e * H_;
  float p = 0.f;
#pragma unroll
  for (int c = s; c < 256; c += 32) {
    float4 xv = *(const float4*)(cls + 4 * c);
    float4 wv = *(const float4*)(w + 4 * c);
    p += xv.x * wv.x + xv.y * wv.y + xv.z * wv.z + xv.w * wv.w;
  }
#pragma unroll
  for (int off = 16; off; off >>= 1) p += __shfl_down(p, off, 32);
  __shared__ float logits[E_];
  if (s == 0) logits[e] = p;
  __syncthreads();
  if (t == 0) {
    float m0 = -1e30f; int i0 = 0;
    for (int j = 0; j < E_; ++j) if (logits[j] > m0) { m0 = logits[j]; i0 = j; }
    float m1 = -1e30f; int i1 = 0;
    for (int j = 0; j < E_; ++j) if (j != i0 && logits[j] > m1) { m1 = logits[j]; i1 = j; }
    float eb = expf(m1 - m0), inv = 1.f / (1.f + eb);
    gws[b * 4 + 0] = inv;
    gws[b * 4 + 1] = eb * inv;
    ((int*)gws)[b * 4 + 2] = i0;
    ((int*)gws)[b * 4 + 3] = i1;
  }
}

// ---------------- gates-only fallback (no-ws path) -------------------------
__global__ __launch_bounds__(256) void moe_gates_kernel(
    const float* __restrict__ x, const float* __restrict__ rw,
    float* __restrict__ gws)
{
  const int b = blockIdx.x;
  const int t = threadIdx.x;
  const int e = t >> 5, s = t & 31;
  const float* cls = x + (size_t)b * L_ * H_;
  const float* w   = rw + (size_t)e * H_;
  float p = 0.f;
#pragma unroll
  for (int c = s; c < 256; c += 32) {
    float4 xv = *(const float4*)(cls + 4 * c);
    float4 wv = *(const float4*)(w + 4 * c);
    p += xv.x * wv.x + xv.y * wv.y + xv.z * wv.z + xv.w * wv.w;
  }
#pragma unroll
  for (int off = 16; off; off >>= 1) p += __shfl_down(p, off, 32);
  __shared__ float logits[E_];
  if (s == 0) logits[e] = p;
  __syncthreads();
  if (t == 0) {
    float m0 = -1e30f; int i0 = 0;
    for (int j = 0; j < E_; ++j) if (logits[j] > m0) { m0 = logits[j]; i0 = j; }
    float m1 = -1e30f; int i1 = 0;
    for (int j = 0; j < E_; ++j) if (j != i0 && logits[j] > m1) { m1 = logits[j]; i1 = j; }
    float eb = expf(m1 - m0), inv = 1.f / (1.f + eb);
    gws[b * 4 + 0] = inv;
    gws[b * 4 + 1] = eb * inv;
    ((int*)gws)[b * 4 + 2] = i0;
    ((int*)gws)[b * 4 + 3] = i1;
  }
}

// ---------------- main: wave-local staging (NO stage barrier) --------------
// Wave w stages ONLY its own 128-col slice (16 rows x 512B, coalesced) of
// the x tile -- exactly the columns its phase A (K-slice) and phase B
// (h-slice) consume. Stage->A is a wave-local LDS dependency, so waves
// drift out of phase naturally: the chip-wide read stream de-phase-locks
// (R18 ablation: shell streams at probe rate; phase-locked compute epochs
// were the ~2x BW loss). Barriers: after dgf-zero, after A's atomics, and
// before the row-crossing epilogue. Pack phase deleted: each lane reads its
// 8 gated dfrag values directly from dgf. Phase math R14/R15-verbatim.
template<int BW>
__global__ __launch_bounds__(512, 8) void moe_main_kernel(
    const float* __restrict__ x,
    const __bf16* __restrict__ ldb, const __bf16* __restrict__ lub,
    const float* __restrict__ ldf, const float* __restrict__ luf,
    const float* __restrict__ gws, float* __restrict__ out)
{
  constexpr int XW = 1036;                  // 518 dw/row, %32==6 (bank-spread)
  __shared__ __bf16 xs[16][XW];             // 33,152 B: x in, OUT (bf16) after B
  __shared__ float  dgf[2][16][16];         //  2,048 B: atomic K-reduce of D^T

  const int t    = threadIdx.x;
  const int w    = t >> 6;                  // 0..7
  const int lane = t & 63;
  const int gq   = lane >> 4;
  const int r16  = lane & 15;

  const int bid  = blockIdx.x;
  const int tile = (bid & 7) * 128 + (bid >> 3);   // XCD swizzle (bijective)
  const int b    = tile >> 5;
  const int l0   = (tile & 31) * 16;

  const float g0 = gws[b * 4 + 0];
  const float g1 = gws[b * 4 + 1];
  const int   e0 = ((const int*)gws)[b * 4 + 2];
  const int   e1 = ((const int*)gws)[b * 4 + 3];

  const float* xb = x + ((size_t)b * L_ + l0) * H_;

  // ---- zero atomic accumulator; one cheap barrier (nothing in flight) -----
  ((float*)dgf)[t] = 0.f;
  __syncthreads();

  // ---- stage: wave w stages its OWN col-slice [w*128,(w+1)*128), 16 rows --
  // lanes 0-31 even rows / 32-63 odd rows; 512B contiguous per 32-lane group.
  // NO barrier follows: phase A consumes only this wave's slice (wave-local
  // LDS dependency) -> waves stagger naturally.
  {
    const int hr = lane >> 5;               // 0,1
    const int cc = w * 128 + (lane & 31) * 4;
#pragma unroll
    for (int i = 0; i < 8; ++i) {
      const int row = 2 * i + hr;
      float4 v = *(const float4*)(xb + (size_t)row * H_ + cc);
      bf16x4 bv = { f2b(v.x), f2b(v.y), f2b(v.z), f2b(v.w) };
      *(bf16x4*)&xs[row][cc] = bv;
    }
  }

  // ---- phase A: wave w covers K slice [w*128,(w+1)*128) (own slice) -------
  f32x4 acc0 = {0.f, 0.f, 0.f, 0.f};
  f32x4 acc1 = {0.f, 0.f, 0.f, 0.f};
#pragma unroll
  for (int s = 0; s < 4; ++s) {
    const int kl = w * 128 + s * 32 + 4 * gq;
    bf16x4 xlo = *(const bf16x4*)&xs[r16][kl];
    bf16x4 xhi = *(const bf16x4*)&xs[r16][kl + 16];
    bf16x8 xq = { xlo[0], xlo[1], xlo[2], xlo[3],
                  xhi[0], xhi[1], xhi[2], xhi[3] };
    bf16x8 wf0, wf1;
    if constexpr (BW) {
      const __bf16* w0p = ldb + ((size_t)e0 * R_ + r16) * H_;
      const __bf16* w1p = ldb + ((size_t)e1 * R_ + r16) * H_;
      bf16x4 a0 = *(const bf16x4*)(w0p + kl);
      bf16x4 a1 = *(const bf16x4*)(w0p + kl + 16);
      bf16x4 b0 = *(const bf16x4*)(w1p + kl);
      bf16x4 b1 = *(const bf16x4*)(w1p + kl + 16);
      wf0 = bf16x8{ a0[0],a0[1],a0[2],a0[3], a1[0],a1[1],a1[2],a1[3] };
      wf1 = bf16x8{ b0[0],b0[1],b0[2],b0[3], b1[0],b1[1],b1[2],b1[3] };
    } else {
      const float* w0p = ldf + ((size_t)e0 * R_ + r16) * H_;
      const float* w1p = ldf + ((size_t)e1 * R_ + r16) * H_;
      float4 alo = *(const float4*)(w0p + kl);
      float4 ahi = *(const float4*)(w0p + kl + 16);
      float4 blo = *(const float4*)(w1p + kl);
      float4 bhi = *(const float4*)(w1p + kl + 16);
      wf0 = bf16x8{ f2b(alo.x), f2b(alo.y), f2b(alo.z), f2b(alo.w),
                    f2b(ahi.x), f2b(ahi.y), f2b(ahi.z), f2b(ahi.w) };
      wf1 = bf16x8{ f2b(blo.x), f2b(blo.y), f2b(blo.z), f2b(blo.w),
                    f2b(bhi.x), f2b(bhi.y), f2b(bhi.z), f2b(bhi.w) };
    }
    acc0 = MFMA(wf0, xq, acc0);
    acc1 = MFMA(wf1, xq, acc1);
  }

  // ---- K-reduce via LDS atomics (D^T frag: col=l=r16, row=p=4gq+j) --------
#pragma unroll
  for (int j = 0; j < 4; ++j) {
    atomicAdd(&dgf[0][r16][4 * gq + j], acc0[j]);
    atomicAdd(&dgf[1][r16][4 * gq + j], acc1[j]);
  }
  __syncthreads();                          // all A-atomics visible

  // ---- phase B: dfrag read DIRECTLY from dgf (pack phase deleted) ---------
  bf16x8 dfrag;
#pragma unroll
  for (int j = 0; j < 4; ++j) {
    dfrag[j]     = f2b(dgf[0][r16][4 * gq + j] * g0);   // k=4gq+j     (e0)
    dfrag[4 + j] = f2b(dgf[1][r16][4 * gq + j] * g1);   // k=16+4gq+j  (e1)
  }

#pragma unroll
  for (int nt = 0; nt < 8; ++nt) {
    const int h0 = w * 128 + nt * 16;
    const int ha = h0 + r16;
    bf16x8 uf;
    if constexpr (BW) {
      bf16x4 ulo = *(const bf16x4*)(lub + ((size_t)e0 * H_ + ha) * R_ + 4 * gq);
      bf16x4 uhi = *(const bf16x4*)(lub + ((size_t)e1 * H_ + ha) * R_ + 4 * gq);
      uf = bf16x8{ ulo[0],ulo[1],ulo[2],ulo[3], uhi[0],uhi[1],uhi[2],uhi[3] };
    } else {
      float4 ulo = *(const float4*)(luf + ((size_t)e0 * H_ + ha) * R_ + 4 * gq);
      float4 uhi = *(const float4*)(luf + ((size_t)e1 * H_ + ha) * R_ + 4 * gq);
      uf = bf16x8{ f2b(ulo.x), f2b(ulo.y), f2b(ulo.z), f2b(ulo.w),
                   f2b(uhi.x), f2b(uhi.y), f2b(uhi.z), f2b(uhi.w) };
    }
    bf16x4 rx = *(const bf16x4*)&xs[r16][h0 + 4 * gq];    // residual (bf16)
    f32x4 acc = { (float)rx[0], (float)rx[1], (float)rx[2], (float)rx[3] };
    acc = MFMA(uf, dfrag, acc);
    bf16x4 ov = { f2b(acc[0]), f2b(acc[1]), f2b(acc[2]), f2b(acc[3]) };
    *(bf16x4*)&xs[r16][h0 + 4 * gq] = ov;     // in-place: same lane, same quad
  }
  __syncthreads();                          // results visible across waves

  // ---- epilogue: stream whole rows out (512B contiguous per instruction) --
  {
    const int row = 2 * w + (lane >> 5);
    const int l32 = lane & 31;
    float* outrow = out + ((size_t)b * L_ + l0 + row) * H_;
#pragma unroll
    for (int it = 0; it < 8; ++it) {
      const int col = it * 128 + l32 * 4;
      bf16x4 v = *(const bf16x4*)&xs[row][col];
      float4 o = { (float)v[0], (float)v[1], (float)v[2], (float)v[3] };
      *(float4*)(outrow + col) = o;
    }
  }
}

extern "C" void kernel_launch(void* const* d_in, const int* in_sizes, int n_in,
                              void* d_out, int out_size, void* d_ws, size_t ws_size,
                              hipStream_t stream) {
  const float* x  = (const float*)d_in[0];
  const float* rw = (const float*)d_in[1];
  const float* ld = (const float*)d_in[2];
  const float* lu = (const float*)d_in[3];
  float* outp = (float*)d_out;

  float*  gws = (float*)d_ws;                         // 512 B
  __bf16* ldb = (__bf16*)((char*)d_ws + 1024);        // 256 KB
  __bf16* lub = ldb + 131072;                         // 256 KB

  if (ws_size >= 1024 + 2 * 131072 * sizeof(__bf16)) {
    hipLaunchKernelGGL(moe_prep_kernel, dim3(256 + B_), dim3(256), 0, stream,
                       x, rw, ld, lu, ldb, lub, gws);
    hipLaunchKernelGGL(moe_main_kernel<1>, dim3(1024), dim3(512), 0, stream,
                       x, ldb, lub, nullptr, nullptr, gws, outp);
  } else {
    hipLaunchKernelGGL(moe_gates_kernel, dim3(B_), dim3(256), 0, stream,
                       x, rw, gws);
    hipLaunchKernelGGL(moe_main_kernel<0>, dim3(1024), dim3(512), 0, stream,
                       x, nullptr, nullptr, ld, lu, gws, outp);
  }
}